// Round 14
// baseline (512.846 us; speedup 1.0000x reference)
//
#include <hip/hip_runtime.h>
#include <hip/hip_bf16.h>

#define T_TOK 2048
#define H_DIM 2048
#define F_DIM 1408
#define N_EXP 8
#define BM 256
#define BN 128
#define BK 64

#define NITEM 24                 // max sum ceil(cnt_e/256) = 23
#define G1_NY (F_DIM / BN)       // 11
#define G2_NY (H_DIM / BN)       // 16
#define G1_CHUNK ((NITEM * G1_NY) / 8)  // 33
#define G2_CHUNK ((NITEM * G2_NY) / 8)  // 48

typedef float f32x4 __attribute__((ext_vector_type(4)));
typedef short s16x8 __attribute__((ext_vector_type(8)));
typedef unsigned int u32;

// swizzled LDS byte offset: rows are 128B (64 bf16); XOR bits[4:6] with row&7
#define LOFF(row, kbyte) (((row) << 7) + ((kbyte) ^ (((row) & 7) << 4)))

__device__ __forceinline__ int bf2i(__hip_bfloat162 h) {
  int r; __builtin_memcpy(&r, &h, 4); return r;
}

__device__ __forceinline__ int4 pack8(float4 a, float4 b) {
  int4 r;
  r.x = bf2i(__float22bfloat162_rn(float2{a.x, a.y}));
  r.y = bf2i(__float22bfloat162_rn(float2{a.z, a.w}));
  r.z = bf2i(__float22bfloat162_rn(float2{b.x, b.y}));
  r.w = bf2i(__float22bfloat162_rn(float2{b.z, b.w}));
  return r;
}

__device__ __forceinline__ unsigned short f2bf(float f) {
  __hip_bfloat16 h = __float2bfloat16(f);
  unsigned short r; __builtin_memcpy(&r, &h, 2); return r;
}

__device__ __forceinline__ f32x4 mfma16(s16x8 a, s16x8 b, f32x4 c) {
  return __builtin_amdgcn_mfma_f32_16x16x32_bf16(a, b, c, 0, 0, 0);
}

// async global->LDS 16B per lane; LDS dest = wave-uniform base + lane*16
__device__ __forceinline__ void dma16(const unsigned short* g, unsigned short* l) {
  __builtin_amdgcn_global_load_lds((const __attribute__((address_space(1))) u32*)g,
                                   (__attribute__((address_space(3))) u32*)l, 16, 0, 0);
}

// ---------------- router (+ fused x->bf16 cast) ----------------
__global__ void router_kernel(const float* __restrict__ x, const float* __restrict__ gw,
                              float* __restrict__ logits, int* __restrict__ tk_idx,
                              float* __restrict__ tk_w, unsigned short* __restrict__ xb) {
  __shared__ float xs[H_DIM];
  __shared__ float lg[N_EXP];
  const int t = blockIdx.x;
  const int tid = threadIdx.x;
  const float4 xv = ((const float4*)(x + (size_t)t * H_DIM))[tid];
  ((float4*)xs)[tid] = xv;
  int2 cw;
  cw.x = bf2i(__float22bfloat162_rn(float2{xv.x, xv.y}));
  cw.y = bf2i(__float22bfloat162_rn(float2{xv.z, xv.w}));
  ((int2*)(xb + (size_t)t * H_DIM))[tid] = cw;
  __syncthreads();
  const int w = tid >> 6, l = tid & 63;
  const float* g = gw + w * H_DIM;
  float s = 0.f;
  for (int j = l; j < H_DIM; j += 64) s += xs[j] * g[j];
#pragma unroll
  for (int o = 32; o; o >>= 1) s += __shfl_down(s, o);
  if (l == 0) lg[w] = s;
  __syncthreads();
  if (tid == 0) {
    float mx = lg[0];
#pragma unroll
    for (int i = 1; i < N_EXP; i++) mx = fmaxf(mx, lg[i]);
    float p[N_EXP];
#pragma unroll
    for (int i = 0; i < N_EXP; i++) p[i] = __expf(lg[i] - mx);
    int i0 = 0;
#pragma unroll
    for (int i = 1; i < N_EXP; i++) if (p[i] > p[i0]) i0 = i;
    int i1 = (i0 == 0) ? 1 : 0;
#pragma unroll
    for (int i = 0; i < N_EXP; i++) if (i != i0 && p[i] > p[i1]) i1 = i;
    const float ww = p[i0] + p[i1];
    tk_idx[t * 2] = i0; tk_idx[t * 2 + 1] = i1;
    tk_w[t * 2] = p[i0] / ww; tk_w[t * 2 + 1] = p[i1] / ww;
#pragma unroll
    for (int i = 0; i < N_EXP; i++) logits[t * N_EXP + i] = lg[i];
  }
}

// ---------------- deterministic per-expert list build (1 block/expert) ----------------
__global__ void build_lists(const int* __restrict__ tk_idx, const float* __restrict__ tk_w,
                            int* __restrict__ counts, int* __restrict__ entries,
                            float* __restrict__ wlist) {
  const int e = blockIdx.x;
  const int l = threadIdx.x;
  int base = 0;
  for (int t0 = 0; t0 < T_TOK; t0 += 64) {
    const int t = t0 + l;
    int sel = -1; float w = 0.f;
    const int i0 = tk_idx[t * 2], i1 = tk_idx[t * 2 + 1];
    if (i0 == e) { sel = t * 2; w = tk_w[t * 2]; }
    else if (i1 == e) { sel = t * 2 + 1; w = tk_w[t * 2 + 1]; }
    const unsigned long long mask = __ballot(sel >= 0);
    const int pos = base + __popcll(mask & ((1ull << l) - 1ull));
    if (sel >= 0) { entries[e * T_TOK + pos] = sel; wlist[e * T_TOK + pos] = w; }
    base += __popcll(mask);
  }
  if (l == 0) counts[e] = base;
}

// ---------------- dense work-item table: items[0]=n, items[1+i]=(e<<16)|mtile ----------------
__global__ void build_items(const int* __restrict__ counts, int* __restrict__ items) {
  if (threadIdx.x == 0) {
    int n = 0;
#pragma unroll
    for (int e = 0; e < N_EXP; e++) {
      const int c = counts[e];
      for (int m0 = 0; m0 < c; m0 += BM) items[1 + n++] = (e << 16) | (m0 / BM);
    }
    items[0] = n;
  }
}

// ---------------- GEMM1: 256x128 block, 8 waves, 64x64 wave tile ----------------
// R11 schedule: one barrier/step, write-ahead B double-buffer, counted vmcnt,
// sched_barrier(0) pins prefetch issues above the MFMA cluster.
// Per step issues: 4 A-dma + 8 B-loads. Entry vmcnt(8) keeps newest 8 (B(t+2)),
// drains B(t+1) reg-loads (pack source) and A-dma(t) (MFMA source).
#define G1_MFMA(ARD, BR1, BR3, KBYTE)                                          \
  {                                                                            \
    s16x8 am[4];                                                               \
    _Pragma("unroll")                                                          \
    for (int mi = 0; mi < 4; mi++)                                             \
      am[mi] = *(const s16x8*)((const char*)(ARD) + LOFF(rowA[mi], (KBYTE)));  \
    _Pragma("unroll")                                                          \
    for (int ni = 0; ni < 4; ni++) {                                           \
      const s16x8 bp = *(const s16x8*)((BR1) + LOFF(rowB[ni], (KBYTE)));       \
      const s16x8 bq = *(const s16x8*)((BR3) + LOFF(rowB[ni], (KBYTE)));       \
      _Pragma("unroll")                                                        \
      for (int mi = 0; mi < 4; mi++) {                                         \
        aG[mi][ni] = mfma16(am[mi], bp, aG[mi][ni]);                           \
        aU[mi][ni] = mfma16(am[mi], bq, aU[mi][ni]);                           \
      }                                                                        \
    }                                                                          \
  }

#define G1_STEP(ARD, AWR, BR1, BW1, BR3, BW3, RS1, RS3, KA_, KB_)              \
  {                                                                            \
    asm volatile("s_waitcnt vmcnt(8) lgkmcnt(0)" ::: "memory");                \
    __builtin_amdgcn_s_barrier();                                              \
    *(int4*)((BW1) + offB0) = pack8(RS1[0], RS1[1]);                           \
    *(int4*)((BW1) + offB1) = pack8(RS1[2], RS1[3]);                           \
    *(int4*)((BW3) + offB0) = pack8(RS3[0], RS3[1]);                           \
    *(int4*)((BW3) + offB1) = pack8(RS3[2], RS3[3]);                           \
    {                                                                          \
      const int ka = (KA_);                                                    \
      dma16(ga0 + ka, (AWR) + aw);                                             \
      dma16(ga1 + ka, (AWR) + aw + 512);                                       \
      dma16(ga2 + ka, (AWR) + aw + 1024);                                      \
      dma16(ga3 + ka, (AWR) + aw + 1536);                                      \
      const int kbl = (KB_);                                                   \
      RS1[0] = *(const float4*)(pb1 + kbl);                                    \
      RS1[1] = *(const float4*)(pb1 + kbl + 4);                                \
      RS1[2] = *(const float4*)(pb1 + (size_t)64 * H_DIM + kbl);               \
      RS1[3] = *(const float4*)(pb1 + (size_t)64 * H_DIM + kbl + 4);           \
      RS3[0] = *(const float4*)(pb3 + kbl);                                    \
      RS3[1] = *(const float4*)(pb3 + kbl + 4);                                \
      RS3[2] = *(const float4*)(pb3 + (size_t)64 * H_DIM + kbl);               \
      RS3[3] = *(const float4*)(pb3 + (size_t)64 * H_DIM + kbl + 4);           \
    }                                                                          \
    __builtin_amdgcn_sched_barrier(0);                                         \
    G1_MFMA(ARD, BR1, BR3, kb);                                                \
    G1_MFMA(ARD, BR1, BR3, 64 + kb);                                           \
  }

__global__ __launch_bounds__(512, 2)
void moe_gemm1(const float* __restrict__ w1, const float* __restrict__ w3,
               const unsigned short* __restrict__ xb,
               const int* __restrict__ counts, const int* __restrict__ entries,
               const int* __restrict__ items,
               unsigned short* __restrict__ hb) {
  const int lin = blockIdx.x;
  const int virt = (lin & 7) * G1_CHUNK + (lin >> 3);
  const int ix = virt % NITEM;
  const int iy = virt / NITEM;
  if (ix >= items[0]) return;
  const int it = items[1 + ix];
  const int e = it >> 16;
  const int m0 = (it & 0xffff) * BM;
  const int rem = counts[e] - m0;
  const int n0 = iy * BN;

  __shared__ unsigned short sA[2][BM * BK];   // 2 x 32KB
  __shared__ unsigned short sB1[2][BN * BK];  // 2 x 16KB
  __shared__ unsigned short sB3[2][BN * BK];  // 2 x 16KB
  char* sb10 = (char*)sB1[0]; char* sb11 = (char*)sB1[1];
  char* sb30 = (char*)sB3[0]; char* sb31 = (char*)sB3[1];

  const int tid = threadIdx.x;
  const int lane = tid & 63;
  const int wave = tid >> 6;
  const int wm = wave >> 1, wn = wave & 1;   // 4 x 2 wave grid

  const int* elist = entries + e * T_TOK + m0;

  // B staging: 512 thr, 2 passes (rows r0, r0+64), 16B bf16 (8 f32) each
  const int r0 = tid >> 3;
  const int gc = tid & 7;
  const float* pb1 = w1 + ((size_t)e * F_DIM + n0 + r0) * H_DIM + gc * 8;
  const float* pb3 = w3 + ((size_t)e * F_DIM + n0 + r0) * H_DIM + gc * 8;
  const int offB0 = LOFF(r0, gc * 16);
  const int offB1 = LOFF(r0 + 64, gc * 16);

  // A DMA: wave covers rows wave*32..wave*32+31 via 4 insts (8 rows each);
  // linear dest; global col pre-swizzled so LOFF read sees swizzled layout.
  const int gcolb = (((lane & 7) << 4) ^ (((lane >> 3) & 7) << 4));
  const int abase = wave * 32 + (lane >> 3);
  int t0r = abase, t1r = abase + 8, t2r = abase + 16, t3r = abase + 24;
  t0r = t0r < rem ? t0r : 0; t1r = t1r < rem ? t1r : 0;
  t2r = t2r < rem ? t2r : 0; t3r = t3r < rem ? t3r : 0;
  const unsigned short* ga0 = xb + (size_t)(elist[t0r] >> 1) * H_DIM + (gcolb >> 1);
  const unsigned short* ga1 = xb + (size_t)(elist[t1r] >> 1) * H_DIM + (gcolb >> 1);
  const unsigned short* ga2 = xb + (size_t)(elist[t2r] >> 1) * H_DIM + (gcolb >> 1);
  const unsigned short* ga3 = xb + (size_t)(elist[t3r] >> 1) * H_DIM + (gcolb >> 1);
  const int aw = wave * 2048;  // u16: wave*32 rows * 64

  int rowA[4], rowB[4];
#pragma unroll
  for (int i = 0; i < 4; i++) {
    rowA[i] = wm * 64 + i * 16 + (lane & 15);
    rowB[i] = wn * 64 + i * 16 + (lane & 15);
  }
  const int kb = (lane >> 4) * 16;

  const f32x4 zero = {0.f, 0.f, 0.f, 0.f};
  f32x4 aG[4][4], aU[4][4];
#pragma unroll
  for (int i = 0; i < 4; i++)
#pragma unroll
    for (int j = 0; j < 4; j++) { aG[i][j] = zero; aU[i][j] = zero; }

  // prologue: S1<-B(0)[8]; S0<-B(1)[8]; dmaA(0)[4]; vmcnt(12) drains S1;
  // BL[0]<-S1; S1<-B(2)[8].  in-flight at loop: [S0(B1)x8, dmaA(0)x4, S1(B2)x8]
  float4 S1_1[4], S1_3[4], S0_1[4], S0_3[4];
#pragma unroll
  for (int p = 0; p < 2; p++) {
    S1_1[p * 2]     = *(const float4*)(pb1 + (size_t)(p * 64) * H_DIM);
    S1_1[p * 2 + 1] = *(const float4*)(pb1 + (size_t)(p * 64) * H_DIM + 4);
    S1_3[p * 2]     = *(const float4*)(pb3 + (size_t)(p * 64) * H_DIM);
    S1_3[p * 2 + 1] = *(const float4*)(pb3 + (size_t)(p * 64) * H_DIM + 4);
  }
#pragma unroll
  for (int p = 0; p < 2; p++) {
    S0_1[p * 2]     = *(const float4*)(pb1 + (size_t)(p * 64) * H_DIM + BK);
    S0_1[p * 2 + 1] = *(const float4*)(pb1 + (size_t)(p * 64) * H_DIM + BK + 4);
    S0_3[p * 2]     = *(const float4*)(pb3 + (size_t)(p * 64) * H_DIM + BK);
    S0_3[p * 2 + 1] = *(const float4*)(pb3 + (size_t)(p * 64) * H_DIM + BK + 4);
  }
  dma16(ga0, sA[0] + aw);
  dma16(ga1, sA[0] + aw + 512);
  dma16(ga2, sA[0] + aw + 1024);
  dma16(ga3, sA[0] + aw + 1536);
  asm volatile("s_waitcnt vmcnt(12)" ::: "memory");
  *(int4*)(sb10 + offB0) = pack8(S1_1[0], S1_1[1]);
  *(int4*)(sb10 + offB1) = pack8(S1_1[2], S1_1[3]);
  *(int4*)(sb30 + offB0) = pack8(S1_3[0], S1_3[1]);
  *(int4*)(sb30 + offB1) = pack8(S1_3[2], S1_3[3]);
#pragma unroll
  for (int p = 0; p < 2; p++) {
    S1_1[p * 2]     = *(const float4*)(pb1 + (size_t)(p * 64) * H_DIM + 2 * BK);
    S1_1[p * 2 + 1] = *(const float4*)(pb1 + (size_t)(p * 64) * H_DIM + 2 * BK + 4);
    S1_3[p * 2]     = *(const float4*)(pb3 + (size_t)(p * 64) * H_DIM + 2 * BK);
    S1_3[p * 2 + 1] = *(const float4*)(pb3 + (size_t)(p * 64) * H_DIM + 2 * BK + 4);
  }

  const int NT = H_DIM / BK;  // 32 (even)
  for (int t = 0; t < NT; t += 2) {
    const int ka1 = (t + 1 < NT) ? (t + 1) * BK : 0;
    const int ka2 = (t + 2 < NT) ? (t + 2) * BK : 0;
    const int kb3 = (t + 3 < NT) ? (t + 3) * BK : 0;
    const int kb4 = (t + 4 < NT) ? (t + 4) * BK : 0;
    G1_STEP(sA[0], sA[1], sb10, sb11, sb30, sb31, S0_1, S0_3, ka1, kb3);
    G1_STEP(sA[1], sA[0], sb11, sb10, sb31, sb30, S1_1, S1_3, ka2, kb4);
  }

  // epilogue: h = silu(g)*u -> bf16 scatter by entry row
#pragma unroll
  for (int mi = 0; mi < 4; mi++) {
#pragma unroll
    for (int r = 0; r < 4; r++) {
      const int m = wm * 64 + mi * 16 + (lane >> 4) * 4 + r;
      if (m < rem) {
        const int entry = elist[m];
        unsigned short* hp = hb + (size_t)entry * F_DIM + n0 + wn * 64 + (lane & 15);
#pragma unroll
        for (int ni = 0; ni < 4; ni++) {
          const float g = aG[mi][ni][r];
          const float u = aU[mi][ni][r];
          hp[ni * 16] = f2bf(g / (1.f + __expf(-g)) * u);
        }
      }
    }
  }
}

// ---------------- GEMM2: 256x128 block, 8 waves, 64x64 wave tile ----------------
#define G2_MFMA(ARD, BR, KBYTE)                                                \
  {                                                                            \
    s16x8 am[4];                                                               \
    _Pragma("unroll")                                                          \
    for (int mi = 0; mi < 4; mi++)                                             \
      am[mi] = *(const s16x8*)((const char*)(ARD) + LOFF(rowA[mi], (KBYTE)));  \
    _Pragma("unroll")                                                          \
    for (int ni = 0; ni < 4; ni++) {                                           \
      const s16x8 bf = *(const s16x8*)((BR) + LOFF(rowB[ni], (KBYTE)));        \
      _Pragma("unroll")                                                        \
      for (int mi = 0; mi < 4; mi++)                                           \
        ac[mi][ni] = mfma16(am[mi], bf, ac[mi][ni]);                           \
    }                                                                          \
  }

#define G2_STEP(ARD, AWR, BR, BW, RS, KA_, KB_)                                \
  {                                                                            \
    asm volatile("s_waitcnt vmcnt(4) lgkmcnt(0)" ::: "memory");                \
    __builtin_amdgcn_s_barrier();                                              \
    *(int4*)((BW) + offB0) = pack8(RS[0], RS[1]);                              \
    *(int4*)((BW) + offB1) = pack8(RS[2], RS[3]);                              \
    {                                                                          \
      const int ka = (KA_);                                                    \
      dma16(ga0 + ka, (AWR) + aw);                                             \
      dma16(ga1 + ka, (AWR) + aw + 512);                                       \
      dma16(ga2 + ka, (AWR) + aw + 1024);                                      \
      dma16(ga3 + ka, (AWR) + aw + 1536);                                      \
      const int kbl = (KB_);                                                   \
      RS[0] = *(const float4*)(pb + kbl);                                      \
      RS[1] = *(const float4*)(pb + kbl + 4);                                  \
      RS[2] = *(const float4*)(pb + (size_t)64 * F_DIM + kbl);                 \
      RS[3] = *(const float4*)(pb + (size_t)64 * F_DIM + kbl + 4);             \
    }                                                                          \
    __builtin_amdgcn_sched_barrier(0);                                         \
    G2_MFMA(ARD, BR, kb);                                                      \
    G2_MFMA(ARD, BR, 64 + kb);                                                 \
  }

__global__ __launch_bounds__(512, 2)
void moe_gemm2(const float* __restrict__ w2,
               const unsigned short* __restrict__ hb,
               const int* __restrict__ counts, const int* __restrict__ entries,
               const float* __restrict__ wlist, const int* __restrict__ items,
               float* __restrict__ out) {
  const int lin = blockIdx.x;
  const int virt = (lin & 7) * G2_CHUNK + (lin >> 3);
  const int ix = virt % NITEM;
  const int iy = virt / NITEM;
  if (ix >= items[0]) return;
  const int it = items[1 + ix];
  const int e = it >> 16;
  const int m0 = (it & 0xffff) * BM;
  const int rem = counts[e] - m0;
  const int n0 = iy * BN;

  __shared__ unsigned short sA[2][BM * BK];  // 2 x 32KB
  __shared__ unsigned short sB[2][BN * BK];  // 2 x 16KB
  char* sb0 = (char*)sB[0]; char* sb1 = (char*)sB[1];

  const int tid = threadIdx.x;
  const int lane = tid & 63;
  const int wave = tid >> 6;
  const int wm = wave >> 1, wn = wave & 1;

  const int* elist = entries + e * T_TOK + m0;
  const float* wl = wlist + e * T_TOK + m0;

  const int r0 = tid >> 3;
  const int gc = tid & 7;
  const float* pb = w2 + ((size_t)e * H_DIM + n0 + r0) * F_DIM + gc * 8;
  const int offB0 = LOFF(r0, gc * 16);
  const int offB1 = LOFF(r0 + 64, gc * 16);

  const int gcolb = (((lane & 7) << 4) ^ (((lane >> 3) & 7) << 4));
  const int abase = wave * 32 + (lane >> 3);
  int t0r = abase, t1r = abase + 8, t2r = abase + 16, t3r = abase + 24;
  t0r = t0r < rem ? t0r : 0; t1r = t1r < rem ? t1r : 0;
  t2r = t2r < rem ? t2r : 0; t3r = t3r < rem ? t3r : 0;
  const unsigned short* ga0 = hb + (size_t)elist[t0r] * F_DIM + (gcolb >> 1);
  const unsigned short* ga1 = hb + (size_t)elist[t1r] * F_DIM + (gcolb >> 1);
  const unsigned short* ga2 = hb + (size_t)elist[t2r] * F_DIM + (gcolb >> 1);
  const unsigned short* ga3 = hb + (size_t)elist[t3r] * F_DIM + (gcolb >> 1);
  const int aw = wave * 2048;

  int rowA[4], rowB[4];
#pragma unroll
  for (int i = 0; i < 4; i++) {
    rowA[i] = wm * 64 + i * 16 + (lane & 15);
    rowB[i] = wn * 64 + i * 16 + (lane & 15);
  }
  const int kb = (lane >> 4) * 16;

  const f32x4 zero = {0.f, 0.f, 0.f, 0.f};
  f32x4 ac[4][4];
#pragma unroll
  for (int i = 0; i < 4; i++)
#pragma unroll
    for (int j = 0; j < 4; j++) ac[i][j] = zero;

  // prologue: S1<-B(0)[4]; S0<-B(1)[4]; dmaA(0)[4]; vmcnt(8) drains S1;
  // BL[0]<-S1; S1<-B(2)[4].
  float4 S1r[4], S0r[4];
#pragma unroll
  for (int p = 0; p < 2; p++) {
    S1r[p * 2]     = *(const float4*)(pb + (size_t)(p * 64) * F_DIM);
    S1r[p * 2 + 1] = *(const float4*)(pb + (size_t)(p * 64) * F_DIM + 4);
  }
#pragma unroll
  for (int p = 0; p < 2; p++) {
    S0r[p * 2]     = *(const float4*)(pb + (size_t)(p * 64) * F_DIM + BK);
    S0r[p * 2 + 1] = *(const float4*)(pb + (size_t)(p * 64) * F_DIM + BK + 4);
  }
  dma16(ga0, sA[0] + aw);
  dma16(ga1, sA[0] + aw + 512);
  dma16(ga2, sA[0] + aw + 1024);
  dma16(ga3, sA[0] + aw + 1536);
  asm volatile("s_waitcnt vmcnt(8)" ::: "memory");
  *(int4*)(sb0 + offB0) = pack8(S1r[0], S1r[1]);
  *(int4*)(sb0 + offB1) = pack8(S1r[2], S1r[3]);
#pragma unroll
  for (int p = 0; p < 2; p++) {
    S1r[p * 2]     = *(const float4*)(pb + (size_t)(p * 64) * F_DIM + 2 * BK);
    S1r[p * 2 + 1] = *(const float4*)(pb + (size_t)(p * 64) * F_DIM + 2 * BK + 4);
  }

  const int NT = F_DIM / BK;  // 22 (even)
  for (int t = 0; t < NT; t += 2) {
    const int ka1 = (t + 1 < NT) ? (t + 1) * BK : 0;
    const int ka2 = (t + 2 < NT) ? (t + 2) * BK : 0;
    const int kb3 = (t + 3 < NT) ? (t + 3) * BK : 0;
    const int kb4 = (t + 4 < NT) ? (t + 4) * BK : 0;
    G2_STEP(sA[0], sA[1], sb0, sb1, S0r, ka1, kb3);
    G2_STEP(sA[1], sA[0], sb1, sb0, S1r, ka2, kb4);
  }

#pragma unroll
  for (int mi = 0; mi < 4; mi++) {
#pragma unroll
    for (int r = 0; r < 4; r++) {
      const int m = wm * 64 + mi * 16 + (lane >> 4) * 4 + r;
      if (m < rem) {
        const int entry = elist[m];
        const int tok = entry >> 1;
        const float wgt = wl[m];
        float* op = out + (size_t)tok * H_DIM + n0 + wn * 64 + (lane & 15);
#pragma unroll
        for (int ni = 0; ni < 4; ni++) atomicAdd(op + ni * 16, wgt * ac[mi][ni][r]);
      }
    }
  }
}

extern "C" void kernel_launch(void* const* d_in, const int* in_sizes, int n_in,
                              void* d_out, int out_size, void* d_ws, size_t ws_size,
                              hipStream_t stream) {
  const float* x  = (const float*)d_in[0];
  const float* gw = (const float*)d_in[1];
  const float* w1 = (const float*)d_in[2];
  const float* w3 = (const float*)d_in[3];
  const float* w2 = (const float*)d_in[4];
  float* out = (float*)d_out;
  float* logits = out + (size_t)T_TOK * H_DIM;

  char* ws = (char*)d_ws;
  size_t off = 0;
  unsigned short* xb = (unsigned short*)(ws + off); off += (size_t)T_TOK * H_DIM * 2;      // 8 MB
  unsigned short* hb = (unsigned short*)(ws + off); off += (size_t)T_TOK * 2 * F_DIM * 2;  // 11.5 MB
  int*   tk_idx = (int*)(ws + off);   off += (size_t)T_TOK * 2 * 4;
  float* tk_w   = (float*)(ws + off); off += (size_t)T_TOK * 2 * 4;
  int*   counts = (int*)(ws + off);   off += 256;
  int*   entries = (int*)(ws + off);  off += (size_t)N_EXP * T_TOK * 4;
  float* wlist  = (float*)(ws + off); off += (size_t)N_EXP * T_TOK * 4;
  int*   items  = (int*)(ws + off);   off += 256;

  (void)hipMemsetAsync(d_out, 0, (size_t)out_size * sizeof(float), stream);
  router_kernel<<<dim3(T_TOK), 512, 0, stream>>>(x, gw, logits, tk_idx, tk_w, xb);
  build_lists<<<dim3(N_EXP), 64, 0, stream>>>(tk_idx, tk_w, counts, entries, wlist);
  build_items<<<dim3(1), 64, 0, stream>>>(counts, items);
  moe_gemm1<<<dim3(NITEM * G1_NY), 512, 0, stream>>>(w1, w3, xb, counts, entries, items, hb);
  moe_gemm2<<<dim3(NITEM * G2_NY), 512, 0, stream>>>(w2, hb, counts, entries, wlist, items, out);
}

// Round 15
// 302.334 us; speedup vs baseline: 1.6963x; 1.6963x over previous
//
#include <hip/hip_runtime.h>
#include <hip/hip_bf16.h>

#define T_TOK 2048
#define H_DIM 2048
#define F_DIM 1408
#define N_EXP 8
#define BM 256
#define BK 64
#define BN1 64
#define BN2 128

#define NITEM 24                 // max sum ceil(cnt_e/256) = 23
#define G1_NY (F_DIM / BN1)      // 22
#define G2_NY (H_DIM / BN2)      // 16
#define G1_CHUNK ((NITEM * G1_NY) / 8)  // 66
#define G2_CHUNK ((NITEM * G2_NY) / 8)  // 48

typedef float f32x4 __attribute__((ext_vector_type(4)));
typedef short s16x8 __attribute__((ext_vector_type(8)));
typedef unsigned int u32;

// swizzled LDS byte offset: rows are 128B (64 bf16); XOR bits[4:6] with row&7
#define LOFF(row, kbyte) (((row) << 7) + ((kbyte) ^ (((row) & 7) << 4)))

__device__ __forceinline__ int bf2i(__hip_bfloat162 h) {
  int r; __builtin_memcpy(&r, &h, 4); return r;
}

__device__ __forceinline__ int4 pack8(float4 a, float4 b) {
  int4 r;
  r.x = bf2i(__float22bfloat162_rn(float2{a.x, a.y}));
  r.y = bf2i(__float22bfloat162_rn(float2{a.z, a.w}));
  r.z = bf2i(__float22bfloat162_rn(float2{b.x, b.y}));
  r.w = bf2i(__float22bfloat162_rn(float2{b.z, b.w}));
  return r;
}

__device__ __forceinline__ unsigned short f2bf(float f) {
  __hip_bfloat16 h = __float2bfloat16(f);
  unsigned short r; __builtin_memcpy(&r, &h, 2); return r;
}

__device__ __forceinline__ f32x4 mfma16(s16x8 a, s16x8 b, f32x4 c) {
  return __builtin_amdgcn_mfma_f32_16x16x32_bf16(a, b, c, 0, 0, 0);
}

// async global->LDS 16B per lane; LDS dest = wave-uniform base + lane*16
__device__ __forceinline__ void dma16(const unsigned short* g, unsigned short* l) {
  __builtin_amdgcn_global_load_lds((const __attribute__((address_space(1))) u32*)g,
                                   (__attribute__((address_space(3))) u32*)l, 16, 0, 0);
}

// ---------------- router (+ fused x->bf16 cast) ----------------
__global__ void router_kernel(const float* __restrict__ x, const float* __restrict__ gw,
                              float* __restrict__ logits, int* __restrict__ tk_idx,
                              float* __restrict__ tk_w, unsigned short* __restrict__ xb) {
  __shared__ float xs[H_DIM];
  __shared__ float lg[N_EXP];
  const int t = blockIdx.x;
  const int tid = threadIdx.x;
  const float4 xv = ((const float4*)(x + (size_t)t * H_DIM))[tid];
  ((float4*)xs)[tid] = xv;
  int2 cw;
  cw.x = bf2i(__float22bfloat162_rn(float2{xv.x, xv.y}));
  cw.y = bf2i(__float22bfloat162_rn(float2{xv.z, xv.w}));
  ((int2*)(xb + (size_t)t * H_DIM))[tid] = cw;
  __syncthreads();
  const int w = tid >> 6, l = tid & 63;
  const float* g = gw + w * H_DIM;
  float s = 0.f;
  for (int j = l; j < H_DIM; j += 64) s += xs[j] * g[j];
#pragma unroll
  for (int o = 32; o; o >>= 1) s += __shfl_down(s, o);
  if (l == 0) lg[w] = s;
  __syncthreads();
  if (tid == 0) {
    float mx = lg[0];
#pragma unroll
    for (int i = 1; i < N_EXP; i++) mx = fmaxf(mx, lg[i]);
    float p[N_EXP];
#pragma unroll
    for (int i = 0; i < N_EXP; i++) p[i] = __expf(lg[i] - mx);
    int i0 = 0;
#pragma unroll
    for (int i = 1; i < N_EXP; i++) if (p[i] > p[i0]) i0 = i;
    int i1 = (i0 == 0) ? 1 : 0;
#pragma unroll
    for (int i = 0; i < N_EXP; i++) if (i != i0 && p[i] > p[i1]) i1 = i;
    const float ww = p[i0] + p[i1];
    tk_idx[t * 2] = i0; tk_idx[t * 2 + 1] = i1;
    tk_w[t * 2] = p[i0] / ww; tk_w[t * 2 + 1] = p[i1] / ww;
#pragma unroll
    for (int i = 0; i < N_EXP; i++) logits[t * N_EXP + i] = lg[i];
  }
}

// ---------------- deterministic per-expert list build (1 block/expert) ----------------
__global__ void build_lists(const int* __restrict__ tk_idx, const float* __restrict__ tk_w,
                            int* __restrict__ counts, int* __restrict__ entries,
                            float* __restrict__ wlist) {
  const int e = blockIdx.x;
  const int l = threadIdx.x;
  int base = 0;
  for (int t0 = 0; t0 < T_TOK; t0 += 64) {
    const int t = t0 + l;
    int sel = -1; float w = 0.f;
    const int i0 = tk_idx[t * 2], i1 = tk_idx[t * 2 + 1];
    if (i0 == e) { sel = t * 2; w = tk_w[t * 2]; }
    else if (i1 == e) { sel = t * 2 + 1; w = tk_w[t * 2 + 1]; }
    const unsigned long long mask = __ballot(sel >= 0);
    const int pos = base + __popcll(mask & ((1ull << l) - 1ull));
    if (sel >= 0) { entries[e * T_TOK + pos] = sel; wlist[e * T_TOK + pos] = w; }
    base += __popcll(mask);
  }
  if (l == 0) counts[e] = base;
}

// ---------------- dense work-item table: items[0]=n, items[1+i]=(e<<16)|mtile ----------------
__global__ void build_items(const int* __restrict__ counts, int* __restrict__ items) {
  if (threadIdx.x == 0) {
    int n = 0;
#pragma unroll
    for (int e = 0; e < N_EXP; e++) {
      const int c = counts[e];
      for (int m0 = 0; m0 < c; m0 += BM) items[1 + n++] = (e << 16) | (m0 / BM);
    }
    items[0] = n;
  }
}

// ---------------- GEMM1: 256x64 block, 8 waves (4x2), wave tile 64x32, G+U ----------------
// R11 schedule: one barrier/step, write-ahead B double-buffer, counted vmcnt,
// sched_barrier(0) pins prefetch issues above MFMAs.
// Per step issues: 4 A-dma + 4 B reg-loads -> entry vmcnt(4) keeps newest 4.
// acc = aG[4][2]+aU[4][2] = 64 regs; staging = 8 float4 = 32 regs (no spill).
#define G1_STEP(ARD, AWR, BR1, BW1, BR3, BW3, RS1, RS3, KA_, KB_)              \
  {                                                                            \
    asm volatile("s_waitcnt vmcnt(4) lgkmcnt(0)" ::: "memory");                \
    __builtin_amdgcn_s_barrier();                                              \
    *(int4*)((BW1) + offB) = pack8(RS1[0], RS1[1]);                            \
    *(int4*)((BW3) + offB) = pack8(RS3[0], RS3[1]);                            \
    {                                                                          \
      const int ka = (KA_);                                                    \
      dma16(ga0 + ka, (AWR) + aw);                                             \
      dma16(ga1 + ka, (AWR) + aw + 512);                                       \
      dma16(ga2 + ka, (AWR) + aw + 1024);                                      \
      dma16(ga3 + ka, (AWR) + aw + 1536);                                      \
      const int kbl = (KB_);                                                   \
      RS1[0] = *(const float4*)(pb1 + kbl);                                    \
      RS1[1] = *(const float4*)(pb1 + kbl + 4);                                \
      RS3[0] = *(const float4*)(pb3 + kbl);                                    \
      RS3[1] = *(const float4*)(pb3 + kbl + 4);                                \
    }                                                                          \
    __builtin_amdgcn_sched_barrier(0);                                         \
    _Pragma("unroll")                                                          \
    for (int kk = 0; kk < 2; kk++) {                                           \
      const int kbyte = kk * 64 + kb;                                          \
      s16x8 am[4];                                                             \
      _Pragma("unroll")                                                        \
      for (int mi = 0; mi < 4; mi++)                                           \
        am[mi] = *(const s16x8*)((const char*)(ARD) + LOFF(rowA[mi], kbyte));  \
      _Pragma("unroll")                                                        \
      for (int ni = 0; ni < 2; ni++) {                                         \
        const s16x8 bp = *(const s16x8*)((BR1) + LOFF(rowB[ni], kbyte));       \
        const s16x8 bq = *(const s16x8*)((BR3) + LOFF(rowB[ni], kbyte));       \
        _Pragma("unroll")                                                      \
        for (int mi = 0; mi < 4; mi++) {                                       \
          aG[mi][ni] = mfma16(am[mi], bp, aG[mi][ni]);                         \
          aU[mi][ni] = mfma16(am[mi], bq, aU[mi][ni]);                         \
        }                                                                      \
      }                                                                        \
    }                                                                          \
  }

__global__ __launch_bounds__(512)
void moe_gemm1(const float* __restrict__ w1, const float* __restrict__ w3,
               const unsigned short* __restrict__ xb,
               const int* __restrict__ counts, const int* __restrict__ entries,
               const int* __restrict__ items,
               unsigned short* __restrict__ hb) {
  const int lin = blockIdx.x;
  const int virt = (lin & 7) * G1_CHUNK + (lin >> 3);
  const int ix = virt % NITEM;
  const int iy = virt / NITEM;
  if (ix >= items[0]) return;
  const int it = items[1 + ix];
  const int e = it >> 16;
  const int m0 = (it & 0xffff) * BM;
  const int rem = counts[e] - m0;
  const int n0 = iy * BN1;

  __shared__ unsigned short sA[2][BM * BK];    // 2 x 32KB
  __shared__ unsigned short sB1[2][BN1 * BK];  // 2 x 8KB
  __shared__ unsigned short sB3[2][BN1 * BK];  // 2 x 8KB
  char* sb10 = (char*)sB1[0]; char* sb11 = (char*)sB1[1];
  char* sb30 = (char*)sB3[0]; char* sb31 = (char*)sB3[1];

  const int tid = threadIdx.x;
  const int lane = tid & 63;
  const int wave = tid >> 6;
  const int wm = wave >> 1, wn = wave & 1;   // 4m x 2n

  const int* elist = entries + e * T_TOK + m0;

  // B staging: 512 thr, row r0 in [0,64), 16B bf16 (8 f32) each, 1 store/matrix
  const int r0 = tid >> 3;
  const int gc = tid & 7;
  const float* pb1 = w1 + ((size_t)e * F_DIM + n0 + r0) * H_DIM + gc * 8;
  const float* pb3 = w3 + ((size_t)e * F_DIM + n0 + r0) * H_DIM + gc * 8;
  const int offB = LOFF(r0, gc * 16);

  // A DMA: wave covers rows wave*32..+31 via 4 insts; linear dest; pre-swizzled src col
  const int gcolb = (((lane & 7) << 4) ^ (((lane >> 3) & 7) << 4));
  const int abase = wave * 32 + (lane >> 3);
  int t0r = abase, t1r = abase + 8, t2r = abase + 16, t3r = abase + 24;
  t0r = t0r < rem ? t0r : 0; t1r = t1r < rem ? t1r : 0;
  t2r = t2r < rem ? t2r : 0; t3r = t3r < rem ? t3r : 0;
  const unsigned short* ga0 = xb + (size_t)(elist[t0r] >> 1) * H_DIM + (gcolb >> 1);
  const unsigned short* ga1 = xb + (size_t)(elist[t1r] >> 1) * H_DIM + (gcolb >> 1);
  const unsigned short* ga2 = xb + (size_t)(elist[t2r] >> 1) * H_DIM + (gcolb >> 1);
  const unsigned short* ga3 = xb + (size_t)(elist[t3r] >> 1) * H_DIM + (gcolb >> 1);
  const int aw = wave * 2048;  // u16: wave*32 rows * 64

  int rowA[4], rowB[2];
#pragma unroll
  for (int i = 0; i < 4; i++) rowA[i] = wm * 64 + i * 16 + (lane & 15);
#pragma unroll
  for (int i = 0; i < 2; i++) rowB[i] = wn * 32 + i * 16 + (lane & 15);
  const int kb = (lane >> 4) * 16;

  const f32x4 zero = {0.f, 0.f, 0.f, 0.f};
  f32x4 aG[4][2], aU[4][2];
#pragma unroll
  for (int i = 0; i < 4; i++)
#pragma unroll
    for (int j = 0; j < 2; j++) { aG[i][j] = zero; aU[i][j] = zero; }

  // prologue: S1<-B(0)[4]; S0<-B(1)[4]; dmaA(0)[4]; vmcnt(8) drains S1;
  // BL[0]<-S1; S1<-B(2)[4].  queue at loop: [S0(B1)x4, dmaA(0)x4, S1(B2)x4]
  float4 S1_1[2], S1_3[2], S0_1[2], S0_3[2];
  S1_1[0] = *(const float4*)(pb1);      S1_1[1] = *(const float4*)(pb1 + 4);
  S1_3[0] = *(const float4*)(pb3);      S1_3[1] = *(const float4*)(pb3 + 4);
  S0_1[0] = *(const float4*)(pb1 + BK); S0_1[1] = *(const float4*)(pb1 + BK + 4);
  S0_3[0] = *(const float4*)(pb3 + BK); S0_3[1] = *(const float4*)(pb3 + BK + 4);
  dma16(ga0, sA[0] + aw);
  dma16(ga1, sA[0] + aw + 512);
  dma16(ga2, sA[0] + aw + 1024);
  dma16(ga3, sA[0] + aw + 1536);
  asm volatile("s_waitcnt vmcnt(8)" ::: "memory");
  *(int4*)(sb10 + offB) = pack8(S1_1[0], S1_1[1]);
  *(int4*)(sb30 + offB) = pack8(S1_3[0], S1_3[1]);
  S1_1[0] = *(const float4*)(pb1 + 2 * BK); S1_1[1] = *(const float4*)(pb1 + 2 * BK + 4);
  S1_3[0] = *(const float4*)(pb3 + 2 * BK); S1_3[1] = *(const float4*)(pb3 + 2 * BK + 4);

  const int NT = H_DIM / BK;  // 32 (even)
  for (int t = 0; t < NT; t += 2) {
    const int ka1 = (t + 1 < NT) ? (t + 1) * BK : 0;
    const int ka2 = (t + 2 < NT) ? (t + 2) * BK : 0;
    const int kb3 = (t + 3 < NT) ? (t + 3) * BK : 0;
    const int kb4 = (t + 4 < NT) ? (t + 4) * BK : 0;
    G1_STEP(sA[0], sA[1], sb10, sb11, sb30, sb31, S0_1, S0_3, ka1, kb3);
    G1_STEP(sA[1], sA[0], sb11, sb10, sb31, sb30, S1_1, S1_3, ka2, kb4);
  }

  // epilogue: h = silu(g)*u -> bf16 scatter by entry row
#pragma unroll
  for (int mi = 0; mi < 4; mi++) {
#pragma unroll
    for (int r = 0; r < 4; r++) {
      const int m = wm * 64 + mi * 16 + (lane >> 4) * 4 + r;
      if (m < rem) {
        const int entry = elist[m];
        unsigned short* hp = hb + (size_t)entry * F_DIM + n0 + wn * 32 + (lane & 15);
#pragma unroll
        for (int ni = 0; ni < 2; ni++) {
          const float g = aG[mi][ni][r];
          const float u = aU[mi][ni][r];
          hp[ni * 16] = f2bf(g / (1.f + __expf(-g)) * u);
        }
      }
    }
  }
}

// ---------------- GEMM2: 256x128 block, 8 waves (4x2), wave tile 64x64 ----------------
#define G2_STEP(ARD, AWR, BR, BW, RS, KA_, KB_)                                \
  {                                                                            \
    asm volatile("s_waitcnt vmcnt(4) lgkmcnt(0)" ::: "memory");                \
    __builtin_amdgcn_s_barrier();                                              \
    *(int4*)((BW) + offB0) = pack8(RS[0], RS[1]);                              \
    *(int4*)((BW) + offB1) = pack8(RS[2], RS[3]);                              \
    {                                                                          \
      const int ka = (KA_);                                                    \
      dma16(ga0 + ka, (AWR) + aw);                                             \
      dma16(ga1 + ka, (AWR) + aw + 512);                                       \
      dma16(ga2 + ka, (AWR) + aw + 1024);                                      \
      dma16(ga3 + ka, (AWR) + aw + 1536);                                      \
      const int kbl = (KB_);                                                   \
      RS[0] = *(const float4*)(pb + kbl);                                      \
      RS[1] = *(const float4*)(pb + kbl + 4);                                  \
      RS[2] = *(const float4*)(pb + (size_t)64 * F_DIM + kbl);                 \
      RS[3] = *(const float4*)(pb + (size_t)64 * F_DIM + kbl + 4);             \
    }                                                                          \
    __builtin_amdgcn_sched_barrier(0);                                         \
    _Pragma("unroll")                                                          \
    for (int kk = 0; kk < 2; kk++) {                                           \
      const int kbyte = kk * 64 + kb;                                          \
      s16x8 am[4];                                                             \
      _Pragma("unroll")                                                        \
      for (int mi = 0; mi < 4; mi++)                                           \
        am[mi] = *(const s16x8*)((const char*)(ARD) + LOFF(rowA[mi], kbyte));  \
      _Pragma("unroll")                                                        \
      for (int ni = 0; ni < 4; ni++) {                                         \
        const s16x8 bf = *(const s16x8*)((BR) + LOFF(rowB[ni], kbyte));        \
        _Pragma("unroll")                                                      \
        for (int mi = 0; mi < 4; mi++)                                         \
          ac[mi][ni] = mfma16(am[mi], bf, ac[mi][ni]);                         \
      }                                                                        \
    }                                                                          \
  }

__global__ __launch_bounds__(512)
void moe_gemm2(const float* __restrict__ w2,
               const unsigned short* __restrict__ hb,
               const int* __restrict__ counts, const int* __restrict__ entries,
               const float* __restrict__ wlist, const int* __restrict__ items,
               float* __restrict__ out) {
  const int lin = blockIdx.x;
  const int virt = (lin & 7) * G2_CHUNK + (lin >> 3);
  const int ix = virt % NITEM;
  const int iy = virt / NITEM;
  if (ix >= items[0]) return;
  const int it = items[1 + ix];
  const int e = it >> 16;
  const int m0 = (it & 0xffff) * BM;
  const int rem = counts[e] - m0;
  const int n0 = iy * BN2;

  __shared__ unsigned short sA[2][BM * BK];   // 2 x 32KB
  __shared__ unsigned short sB[2][BN2 * BK];  // 2 x 16KB
  char* sb0 = (char*)sB[0]; char* sb1 = (char*)sB[1];

  const int tid = threadIdx.x;
  const int lane = tid & 63;
  const int wave = tid >> 6;
  const int wm = wave >> 1, wn = wave & 1;

  const int* elist = entries + e * T_TOK + m0;
  const float* wl = wlist + e * T_TOK + m0;

  const int r0 = tid >> 3;
  const int gc = tid & 7;
  const float* pb = w2 + ((size_t)e * H_DIM + n0 + r0) * F_DIM + gc * 8;
  const int offB0 = LOFF(r0, gc * 16);
  const int offB1 = LOFF(r0 + 64, gc * 16);

  const int gcolb = (((lane & 7) << 4) ^ (((lane >> 3) & 7) << 4));
  const int abase = wave * 32 + (lane >> 3);
  int t0r = abase, t1r = abase + 8, t2r = abase + 16, t3r = abase + 24;
  t0r = t0r < rem ? t0r : 0; t1r = t1r < rem ? t1r : 0;
  t2r = t2r < rem ? t2r : 0; t3r = t3r < rem ? t3r : 0;
  const unsigned short* ga0 = hb + (size_t)elist[t0r] * F_DIM + (gcolb >> 1);
  const unsigned short* ga1 = hb + (size_t)elist[t1r] * F_DIM + (gcolb >> 1);
  const unsigned short* ga2 = hb + (size_t)elist[t2r] * F_DIM + (gcolb >> 1);
  const unsigned short* ga3 = hb + (size_t)elist[t3r] * F_DIM + (gcolb >> 1);
  const int aw = wave * 2048;

  int rowA[4], rowB[4];
#pragma unroll
  for (int i = 0; i < 4; i++) {
    rowA[i] = wm * 64 + i * 16 + (lane & 15);
    rowB[i] = wn * 64 + i * 16 + (lane & 15);
  }
  const int kb = (lane >> 4) * 16;

  const f32x4 zero = {0.f, 0.f, 0.f, 0.f};
  f32x4 ac[4][4];
#pragma unroll
  for (int i = 0; i < 4; i++)
#pragma unroll
    for (int j = 0; j < 4; j++) ac[i][j] = zero;

  // prologue: S1<-B(0)[4]; S0<-B(1)[4]; dmaA(0)[4]; vmcnt(8) drains S1;
  // BL[0]<-S1; S1<-B(2)[4].
  float4 S1r[4], S0r[4];
#pragma unroll
  for (int p = 0; p < 2; p++) {
    S1r[p * 2]     = *(const float4*)(pb + (size_t)(p * 64) * F_DIM);
    S1r[p * 2 + 1] = *(const float4*)(pb + (size_t)(p * 64) * F_DIM + 4);
  }
#pragma unroll
  for (int p = 0; p < 2; p++) {
    S0r[p * 2]     = *(const float4*)(pb + (size_t)(p * 64) * F_DIM + BK);
    S0r[p * 2 + 1] = *(const float4*)(pb + (size_t)(p * 64) * F_DIM + BK + 4);
  }
  dma16(ga0, sA[0] + aw);
  dma16(ga1, sA[0] + aw + 512);
  dma16(ga2, sA[0] + aw + 1024);
  dma16(ga3, sA[0] + aw + 1536);
  asm volatile("s_waitcnt vmcnt(8)" ::: "memory");
  *(int4*)(sb0 + offB0) = pack8(S1r[0], S1r[1]);
  *(int4*)(sb0 + offB1) = pack8(S1r[2], S1r[3]);
#pragma unroll
  for (int p = 0; p < 2; p++) {
    S1r[p * 2]     = *(const float4*)(pb + (size_t)(p * 64) * F_DIM + 2 * BK);
    S1r[p * 2 + 1] = *(const float4*)(pb + (size_t)(p * 64) * F_DIM + 2 * BK + 4);
  }

  const int NT = F_DIM / BK;  // 22 (even)
  for (int t = 0; t < NT; t += 2) {
    const int ka1 = (t + 1 < NT) ? (t + 1) * BK : 0;
    const int ka2 = (t + 2 < NT) ? (t + 2) * BK : 0;
    const int kb3 = (t + 3 < NT) ? (t + 3) * BK : 0;
    const int kb4 = (t + 4 < NT) ? (t + 4) * BK : 0;
    G2_STEP(sA[0], sA[1], sb0, sb1, S0r, ka1, kb3);
    G2_STEP(sA[1], sA[0], sb1, sb0, S1r, ka2, kb4);
  }

#pragma unroll
  for (int mi = 0; mi < 4; mi++) {
#pragma unroll
    for (int r = 0; r < 4; r++) {
      const int m = wm * 64 + mi * 16 + (lane >> 4) * 4 + r;
      if (m < rem) {
        const int entry = elist[m];
        const int tok = entry >> 1;
        const float wgt = wl[m];
        float* op = out + (size_t)tok * H_DIM + n0 + wn * 64 + (lane & 15);
#pragma unroll
        for (int ni = 0; ni < 4; ni++) atomicAdd(op + ni * 16, wgt * ac[mi][ni][r]);
      }
    }
  }
}

extern "C" void kernel_launch(void* const* d_in, const int* in_sizes, int n_in,
                              void* d_out, int out_size, void* d_ws, size_t ws_size,
                              hipStream_t stream) {
  const float* x  = (const float*)d_in[0];
  const float* gw = (const float*)d_in[1];
  const float* w1 = (const float*)d_in[2];
  const float* w3 = (const float*)d_in[3];
  const float* w2 = (const float*)d_in[4];
  float* out = (float*)d_out;
  float* logits = out + (size_t)T_TOK * H_DIM;

  char* ws = (char*)d_ws;
  size_t off = 0;
  unsigned short* xb = (unsigned short*)(ws + off); off += (size_t)T_TOK * H_DIM * 2;      // 8 MB
  unsigned short* hb = (unsigned short*)(ws + off); off += (size_t)T_TOK * 2 * F_DIM * 2;  // 11.5 MB
  int*   tk_idx = (int*)(ws + off);   off += (size_t)T_TOK * 2 * 4;
  float* tk_w   = (float*)(ws + off); off += (size_t)T_TOK * 2 * 4;
  int*   counts = (int*)(ws + off);   off += 256;
  int*   entries = (int*)(ws + off);  off += (size_t)N_EXP * T_TOK * 4;
  float* wlist  = (float*)(ws + off); off += (size_t)N_EXP * T_TOK * 4;
  int*   items  = (int*)(ws + off);   off += 256;

  (void)hipMemsetAsync(d_out, 0, (size_t)out_size * sizeof(float), stream);
  router_kernel<<<dim3(T_TOK), 512, 0, stream>>>(x, gw, logits, tk_idx, tk_w, xb);
  build_lists<<<dim3(N_EXP), 64, 0, stream>>>(tk_idx, tk_w, counts, entries, wlist);
  build_items<<<dim3(1), 64, 0, stream>>>(counts, items);
  moe_gemm1<<<dim3(NITEM * G1_NY), 512, 0, stream>>>(w1, w3, xb, counts, entries, items, hb);
  moe_gemm2<<<dim3(NITEM * G2_NY), 512, 0, stream>>>(w2, hb, counts, entries, wlist, items, out);
}

// Round 16
// 233.281 us; speedup vs baseline: 2.1984x; 1.2960x over previous
//
#include <hip/hip_runtime.h>
#include <hip/hip_bf16.h>

#define T_TOK 2048
#define H_DIM 2048
#define F_DIM 1408
#define N_EXP 8
#define BM 128
#define BN 64
#define BK 64

#define NITEM 40
#define G1_NY (F_DIM / BN)   // 22
#define G2_NY (H_DIM / BN)   // 32
#define G1_CHUNK ((NITEM * G1_NY) / 8)  // 110
#define G2_CHUNK ((NITEM * G2_NY) / 8)  // 160

typedef float f32x4 __attribute__((ext_vector_type(4)));
typedef short s16x8 __attribute__((ext_vector_type(8)));
typedef unsigned int u32;

// swizzled LDS byte offset: rows are 128B (64 bf16); XOR bits[4:6] with row&7
#define LOFF(row, kbyte) (((row) << 7) + ((kbyte) ^ (((row) & 7) << 4)))

__device__ __forceinline__ int bf2i(__hip_bfloat162 h) {
  int r; __builtin_memcpy(&r, &h, 4); return r;
}

__device__ __forceinline__ int4 pack8(float4 a, float4 b) {
  int4 r;
  r.x = bf2i(__float22bfloat162_rn(float2{a.x, a.y}));
  r.y = bf2i(__float22bfloat162_rn(float2{a.z, a.w}));
  r.z = bf2i(__float22bfloat162_rn(float2{b.x, b.y}));
  r.w = bf2i(__float22bfloat162_rn(float2{b.z, b.w}));
  return r;
}

__device__ __forceinline__ unsigned short f2bf(float f) {
  __hip_bfloat16 h = __float2bfloat16(f);
  unsigned short r; __builtin_memcpy(&r, &h, 2); return r;
}

__device__ __forceinline__ f32x4 mfma16(s16x8 a, s16x8 b, f32x4 c) {
  return __builtin_amdgcn_mfma_f32_16x16x32_bf16(a, b, c, 0, 0, 0);
}

// async global->LDS 16B per lane; LDS dest = wave-uniform base + lane*16
__device__ __forceinline__ void dma16(const unsigned short* g, unsigned short* l) {
  __builtin_amdgcn_global_load_lds((const __attribute__((address_space(1))) u32*)g,
                                   (__attribute__((address_space(3))) u32*)l, 16, 0, 0);
}

// ---------------- router (+ fused x->bf16 cast) ----------------
__global__ void router_kernel(const float* __restrict__ x, const float* __restrict__ gw,
                              float* __restrict__ logits, int* __restrict__ tk_idx,
                              float* __restrict__ tk_w, unsigned short* __restrict__ xb) {
  __shared__ float xs[H_DIM];
  __shared__ float lg[N_EXP];
  const int t = blockIdx.x;
  const int tid = threadIdx.x;
  const float4 xv = ((const float4*)(x + (size_t)t * H_DIM))[tid];
  ((float4*)xs)[tid] = xv;
  int2 cw;
  cw.x = bf2i(__float22bfloat162_rn(float2{xv.x, xv.y}));
  cw.y = bf2i(__float22bfloat162_rn(float2{xv.z, xv.w}));
  ((int2*)(xb + (size_t)t * H_DIM))[tid] = cw;
  __syncthreads();
  const int w = tid >> 6, l = tid & 63;
  const float* g = gw + w * H_DIM;
  float s = 0.f;
  for (int j = l; j < H_DIM; j += 64) s += xs[j] * g[j];
#pragma unroll
  for (int o = 32; o; o >>= 1) s += __shfl_down(s, o);
  if (l == 0) lg[w] = s;
  __syncthreads();
  if (tid == 0) {
    float mx = lg[0];
#pragma unroll
    for (int i = 1; i < N_EXP; i++) mx = fmaxf(mx, lg[i]);
    float p[N_EXP];
#pragma unroll
    for (int i = 0; i < N_EXP; i++) p[i] = __expf(lg[i] - mx);
    int i0 = 0;
#pragma unroll
    for (int i = 1; i < N_EXP; i++) if (p[i] > p[i0]) i0 = i;
    int i1 = (i0 == 0) ? 1 : 0;
#pragma unroll
    for (int i = 0; i < N_EXP; i++) if (i != i0 && p[i] > p[i1]) i1 = i;
    const float ww = p[i0] + p[i1];
    tk_idx[t * 2] = i0; tk_idx[t * 2 + 1] = i1;
    tk_w[t * 2] = p[i0] / ww; tk_w[t * 2 + 1] = p[i1] / ww;
#pragma unroll
    for (int i = 0; i < N_EXP; i++) logits[t * N_EXP + i] = lg[i];
  }
}

// ---------------- deterministic per-expert list build (1 block/expert) ----------------
__global__ void build_lists(const int* __restrict__ tk_idx, const float* __restrict__ tk_w,
                            int* __restrict__ counts, int* __restrict__ entries,
                            float* __restrict__ wlist) {
  const int e = blockIdx.x;
  const int l = threadIdx.x;
  int base = 0;
  for (int t0 = 0; t0 < T_TOK; t0 += 64) {
    const int t = t0 + l;
    int sel = -1; float w = 0.f;
    const int i0 = tk_idx[t * 2], i1 = tk_idx[t * 2 + 1];
    if (i0 == e) { sel = t * 2; w = tk_w[t * 2]; }
    else if (i1 == e) { sel = t * 2 + 1; w = tk_w[t * 2 + 1]; }
    const unsigned long long mask = __ballot(sel >= 0);
    const int pos = base + __popcll(mask & ((1ull << l) - 1ull));
    if (sel >= 0) { entries[e * T_TOK + pos] = sel; wlist[e * T_TOK + pos] = w; }
    base += __popcll(mask);
  }
  if (l == 0) counts[e] = base;
}

// ---------------- dense work-item table: items[0]=n, items[1+i]=(e<<16)|mtile ----------------
__global__ void build_items(const int* __restrict__ counts, int* __restrict__ items) {
  if (threadIdx.x == 0) {
    int n = 0;
#pragma unroll
    for (int e = 0; e < N_EXP; e++) {
      const int c = counts[e];
      for (int m0 = 0; m0 < c; m0 += BM) items[1 + n++] = (e << 16) | (m0 / BM);
    }
    items[0] = n;
  }
}

// ---------------- GEMM1 ----------------
// R11 schedule + T5 setprio: one barrier/step, write-ahead B double-buffer,
// counted vmcnt, sched_barrier(0) pin, MFMA cluster wrapped in setprio(1)/(0).
#define G1_STEP(ARD, AWR, BLR1, BLW1, BLR3, BLW3, RS1, RS3, KA1_, KB3_)       \
  {                                                                           \
    asm volatile("s_waitcnt vmcnt(4) lgkmcnt(0)" ::: "memory");               \
    __builtin_amdgcn_s_barrier();                                             \
    *(int4*)((BLW1) + offB) = pack8(RS1[0], RS1[1]);                          \
    *(int4*)((BLW3) + offB) = pack8(RS3[0], RS3[1]);                          \
    {                                                                         \
      const int ka = (KA1_);                                                  \
      dma16(ga0 + ka, (AWR) + aw);                                            \
      dma16(ga1 + ka, (AWR) + aw + 512);                                      \
      const int kbl = (KB3_);                                                 \
      RS1[0] = *(const float4*)(pb1 + kbl);                                   \
      RS1[1] = *(const float4*)(pb1 + kbl + 4);                               \
      RS3[0] = *(const float4*)(pb3 + kbl);                                   \
      RS3[1] = *(const float4*)(pb3 + kbl + 4);                               \
    }                                                                         \
    __builtin_amdgcn_sched_barrier(0);                                        \
    __builtin_amdgcn_s_setprio(1);                                            \
    _Pragma("unroll")                                                         \
    for (int kk = 0; kk < 2; kk++) {                                          \
      const int kbyte = kk * 64 + kb;                                         \
      const s16x8 a0 = *(const s16x8*)((const char*)(ARD) + LOFF(rowA0, kbyte)); \
      const s16x8 a1 = *(const s16x8*)((const char*)(ARD) + LOFF(rowA1, kbyte)); \
      const s16x8 p0 = *(const s16x8*)((BLR1) + LOFF(rowB0, kbyte));          \
      const s16x8 p1 = *(const s16x8*)((BLR1) + LOFF(rowB1, kbyte));          \
      const s16x8 q0 = *(const s16x8*)((BLR3) + LOFF(rowB0, kbyte));          \
      const s16x8 q1 = *(const s16x8*)((BLR3) + LOFF(rowB1, kbyte));          \
      aG[0][0] = mfma16(a0, p0, aG[0][0]); aG[0][1] = mfma16(a0, p1, aG[0][1]); \
      aG[1][0] = mfma16(a1, p0, aG[1][0]); aG[1][1] = mfma16(a1, p1, aG[1][1]); \
      aU[0][0] = mfma16(a0, q0, aU[0][0]); aU[0][1] = mfma16(a0, q1, aU[0][1]); \
      aU[1][0] = mfma16(a1, q0, aU[1][0]); aU[1][1] = mfma16(a1, q1, aU[1][1]); \
    }                                                                         \
    __builtin_amdgcn_s_setprio(0);                                            \
  }

__global__ __launch_bounds__(512)
void moe_gemm1(const float* __restrict__ w1, const float* __restrict__ w3,
               const unsigned short* __restrict__ xb,
               const int* __restrict__ counts, const int* __restrict__ entries,
               const int* __restrict__ items,
               unsigned short* __restrict__ hb) {
  const int lin = blockIdx.x;
  const int virt = (lin & 7) * G1_CHUNK + (lin >> 3);
  const int ix = virt % NITEM;
  const int iy = virt / NITEM;
  if (ix >= items[0]) return;
  const int it = items[1 + ix];
  const int e = it >> 16;
  const int m0 = (it & 0xffff) * BM;
  const int rem = counts[e] - m0;
  const int n0 = iy * BN;

  __shared__ unsigned short sA[2][BM * BK];   // 2 x 16KB
  __shared__ unsigned short sB1[2][BN * BK];  // 2 x 8KB
  __shared__ unsigned short sB3[2][BN * BK];  // 2 x 8KB
  char* sb10 = (char*)sB1[0]; char* sb11 = (char*)sB1[1];
  char* sb30 = (char*)sB3[0]; char* sb31 = (char*)sB3[1];

  const int tid = threadIdx.x;
  const int lane = tid & 63;
  const int wave = tid >> 6;
  const int wm = wave >> 1, wn = wave & 1;

  const int* elist = entries + e * T_TOK + m0;

  const int r0 = tid >> 3;
  const int gc = tid & 7;
  const float* pb1 = w1 + ((size_t)e * F_DIM + n0 + r0) * H_DIM + gc * 8;
  const float* pb3 = w3 + ((size_t)e * F_DIM + n0 + r0) * H_DIM + gc * 8;
  const int offB = LOFF(r0, gc * 16);

  const int arow0 = wave * 16 + (lane >> 3);
  const int arow1 = arow0 + 8;
  const int gcolb = (((lane & 7) << 4) ^ (((lane >> 3) & 7) << 4));
  const int tokA0 = elist[arow0 < rem ? arow0 : 0] >> 1;
  const int tokA1 = elist[arow1 < rem ? arow1 : 0] >> 1;
  const unsigned short* ga0 = xb + (size_t)tokA0 * H_DIM + (gcolb >> 1);
  const unsigned short* ga1 = xb + (size_t)tokA1 * H_DIM + (gcolb >> 1);
  const int aw = wave * 1024;  // u16 elems: wave*2048B

  const int rowA0 = wm * 32 + (lane & 15);
  const int rowA1 = rowA0 + 16;
  const int rowB0 = wn * 32 + (lane & 15);
  const int rowB1 = rowB0 + 16;
  const int kb = (lane >> 4) * 16;

  const f32x4 zero = {0.f, 0.f, 0.f, 0.f};
  f32x4 aG[2][2], aU[2][2];
#pragma unroll
  for (int i = 0; i < 2; i++)
#pragma unroll
    for (int j = 0; j < 2; j++) { aG[i][j] = zero; aU[i][j] = zero; }

  // prologue: s1<-B(0)[4]; s0<-B(1)[4]; dmaA(0)[2]; vmcnt(6) drains s1;
  // BL[0]<-s1; s1<-B(2)[4].  queue: [s0 B(1)x4, dmaA(0)x2, s1 B(2)x4] = 10.
  float4 s1_1[2], s1_3[2], s0_1[2], s0_3[2];
  s1_1[0] = *(const float4*)(pb1);      s1_1[1] = *(const float4*)(pb1 + 4);
  s1_3[0] = *(const float4*)(pb3);      s1_3[1] = *(const float4*)(pb3 + 4);
  s0_1[0] = *(const float4*)(pb1 + BK); s0_1[1] = *(const float4*)(pb1 + BK + 4);
  s0_3[0] = *(const float4*)(pb3 + BK); s0_3[1] = *(const float4*)(pb3 + BK + 4);
  dma16(ga0, sA[0] + aw);
  dma16(ga1, sA[0] + aw + 512);
  asm volatile("s_waitcnt vmcnt(6)" ::: "memory");
  *(int4*)(sb10 + offB) = pack8(s1_1[0], s1_1[1]);
  *(int4*)(sb30 + offB) = pack8(s1_3[0], s1_3[1]);
  s1_1[0] = *(const float4*)(pb1 + 2 * BK); s1_1[1] = *(const float4*)(pb1 + 2 * BK + 4);
  s1_3[0] = *(const float4*)(pb3 + 2 * BK); s1_3[1] = *(const float4*)(pb3 + 2 * BK + 4);

  const int NT = H_DIM / BK;  // 32 (even)
  for (int t = 0; t < NT; t += 2) {
    const int ka1 = (t + 1 < NT) ? (t + 1) * BK : 0;
    const int ka2 = (t + 2 < NT) ? (t + 2) * BK : 0;
    const int kb3 = (t + 3 < NT) ? (t + 3) * BK : 0;
    const int kb4 = (t + 4 < NT) ? (t + 4) * BK : 0;
    G1_STEP(sA[0], sA[1], sb10, sb11, sb30, sb31, s0_1, s0_3, ka1, kb3);
    G1_STEP(sA[1], sA[0], sb11, sb10, sb31, sb30, s1_1, s1_3, ka2, kb4);
  }

  // epilogue: h = silu(g)*u -> bf16 scatter by entry row
#pragma unroll
  for (int i = 0; i < 2; i++) {
#pragma unroll
    for (int r = 0; r < 4; r++) {
      const int m = wm * 32 + i * 16 + ((lane >> 4) << 2) + r;
      if (m < rem) {
        const int entry = elist[m];
        unsigned short* hp = hb + (size_t)entry * F_DIM + n0 + wn * 32 + (lane & 15);
#pragma unroll
        for (int j = 0; j < 2; j++) {
          const float g = aG[i][j][r];
          const float u = aU[i][j][r];
          hp[j * 16] = f2bf(g / (1.f + __expf(-g)) * u);
        }
      }
    }
  }
}

// ---------------- GEMM2 ----------------
#define G2_STEP(ARD, AWR, BLR, BLW, RS, KA1_, KB3_)                           \
  {                                                                           \
    asm volatile("s_waitcnt vmcnt(2) lgkmcnt(0)" ::: "memory");               \
    __builtin_amdgcn_s_barrier();                                             \
    *(int4*)((BLW) + offB) = pack8(RS[0], RS[1]);                             \
    {                                                                         \
      const int ka = (KA1_);                                                  \
      dma16(ga0 + ka, (AWR) + aw);                                            \
      dma16(ga1 + ka, (AWR) + aw + 512);                                      \
      const int kbl = (KB3_);                                                 \
      RS[0] = *(const float4*)(pb + kbl);                                     \
      RS[1] = *(const float4*)(pb + kbl + 4);                                 \
    }                                                                         \
    __builtin_amdgcn_sched_barrier(0);                                        \
    __builtin_amdgcn_s_setprio(1);                                            \
    _Pragma("unroll")                                                         \
    for (int kk = 0; kk < 2; kk++) {                                          \
      const int kbyte = kk * 64 + kb;                                         \
      const s16x8 a0 = *(const s16x8*)((const char*)(ARD) + LOFF(rowA0, kbyte)); \
      const s16x8 a1 = *(const s16x8*)((const char*)(ARD) + LOFF(rowA1, kbyte)); \
      const s16x8 f0 = *(const s16x8*)((BLR) + LOFF(rowB0, kbyte));           \
      const s16x8 f1 = *(const s16x8*)((BLR) + LOFF(rowB1, kbyte));           \
      ac[0][0] = mfma16(a0, f0, ac[0][0]); ac[0][1] = mfma16(a0, f1, ac[0][1]); \
      ac[1][0] = mfma16(a1, f0, ac[1][0]); ac[1][1] = mfma16(a1, f1, ac[1][1]); \
    }                                                                         \
    __builtin_amdgcn_s_setprio(0);                                            \
  }

__global__ __launch_bounds__(512)
void moe_gemm2(const float* __restrict__ w2,
               const unsigned short* __restrict__ hb,
               const int* __restrict__ counts, const int* __restrict__ entries,
               const float* __restrict__ wlist, const int* __restrict__ items,
               float* __restrict__ out) {
  const int lin = blockIdx.x;
  const int virt = (lin & 7) * G2_CHUNK + (lin >> 3);
  const int ix = virt % NITEM;
  const int iy = virt / NITEM;
  if (ix >= items[0]) return;
  const int it = items[1 + ix];
  const int e = it >> 16;
  const int m0 = (it & 0xffff) * BM;
  const int rem = counts[e] - m0;
  const int n0 = iy * BN;

  __shared__ unsigned short sA[2][BM * BK];  // 2 x 16KB
  __shared__ unsigned short sB[2][BN * BK];  // 2 x 8KB
  char* sb0 = (char*)sB[0]; char* sb1 = (char*)sB[1];

  const int tid = threadIdx.x;
  const int lane = tid & 63;
  const int wave = tid >> 6;
  const int wm = wave >> 1, wn = wave & 1;

  const int* elist = entries + e * T_TOK + m0;
  const float* wl = wlist + e * T_TOK + m0;

  const int r0 = tid >> 3;
  const int gc = tid & 7;
  const float* pb = w2 + ((size_t)e * H_DIM + n0 + r0) * F_DIM + gc * 8;
  const int offB = LOFF(r0, gc * 16);

  const int arow0 = wave * 16 + (lane >> 3);
  const int arow1 = arow0 + 8;
  const int gcolb = (((lane & 7) << 4) ^ (((lane >> 3) & 7) << 4));
  const int enA0 = elist[arow0 < rem ? arow0 : 0];
  const int enA1 = elist[arow1 < rem ? arow1 : 0];
  const unsigned short* ga0 = hb + (size_t)enA0 * F_DIM + (gcolb >> 1);
  const unsigned short* ga1 = hb + (size_t)enA1 * F_DIM + (gcolb >> 1);
  const int aw = wave * 1024;

  const int rowA0 = wm * 32 + (lane & 15);
  const int rowA1 = rowA0 + 16;
  const int rowB0 = wn * 32 + (lane & 15);
  const int rowB1 = rowB0 + 16;
  const int kb = (lane >> 4) * 16;

  const f32x4 zero = {0.f, 0.f, 0.f, 0.f};
  f32x4 ac[2][2];
#pragma unroll
  for (int i = 0; i < 2; i++)
#pragma unroll
    for (int j = 0; j < 2; j++) ac[i][j] = zero;

  // prologue: s1<-B(0)[2]; s0<-B(1)[2]; dmaA(0)[2]; vmcnt(4) drains s1;
  // BL[0]<-s1; s1<-B(2)[2].  queue: [s0x2, dmax2, s1x2] = 6.
  float4 s1r[2], s0r[2];
  s1r[0] = *(const float4*)(pb);      s1r[1] = *(const float4*)(pb + 4);
  s0r[0] = *(const float4*)(pb + BK); s0r[1] = *(const float4*)(pb + BK + 4);
  dma16(ga0, sA[0] + aw);
  dma16(ga1, sA[0] + aw + 512);
  asm volatile("s_waitcnt vmcnt(4)" ::: "memory");
  *(int4*)(sb0 + offB) = pack8(s1r[0], s1r[1]);
  s1r[0] = *(const float4*)(pb + 2 * BK); s1r[1] = *(const float4*)(pb + 2 * BK + 4);

  const int NT = F_DIM / BK;  // 22 (even)
  for (int t = 0; t < NT; t += 2) {
    const int ka1 = (t + 1 < NT) ? (t + 1) * BK : 0;
    const int ka2 = (t + 2 < NT) ? (t + 2) * BK : 0;
    const int kb3 = (t + 3 < NT) ? (t + 3) * BK : 0;
    const int kb4 = (t + 4 < NT) ? (t + 4) * BK : 0;
    G2_STEP(sA[0], sA[1], sb0, sb1, s0r, ka1, kb3);
    G2_STEP(sA[1], sA[0], sb1, sb0, s1r, ka2, kb4);
  }

#pragma unroll
  for (int i = 0; i < 2; i++) {
#pragma unroll
    for (int r = 0; r < 4; r++) {
      const int m = wm * 32 + i * 16 + ((lane >> 4) << 2) + r;
      if (m < rem) {
        const int entry = elist[m];
        const int tok = entry >> 1;
        const float wgt = wl[m];
        float* op = out + (size_t)tok * H_DIM + n0 + wn * 32 + (lane & 15);
#pragma unroll
        for (int j = 0; j < 2; j++) atomicAdd(op + j * 16, wgt * ac[i][j][r]);
      }
    }
  }
}

extern "C" void kernel_launch(void* const* d_in, const int* in_sizes, int n_in,
                              void* d_out, int out_size, void* d_ws, size_t ws_size,
                              hipStream_t stream) {
  const float* x  = (const float*)d_in[0];
  const float* gw = (const float*)d_in[1];
  const float* w1 = (const float*)d_in[2];
  const float* w3 = (const float*)d_in[3];
  const float* w2 = (const float*)d_in[4];
  float* out = (float*)d_out;
  float* logits = out + (size_t)T_TOK * H_DIM;

  char* ws = (char*)d_ws;
  size_t off = 0;
  unsigned short* xb = (unsigned short*)(ws + off); off += (size_t)T_TOK * H_DIM * 2;      // 8 MB
  unsigned short* hb = (unsigned short*)(ws + off); off += (size_t)T_TOK * 2 * F_DIM * 2;  // 11.5 MB
  int*   tk_idx = (int*)(ws + off);   off += (size_t)T_TOK * 2 * 4;
  float* tk_w   = (float*)(ws + off); off += (size_t)T_TOK * 2 * 4;
  int*   counts = (int*)(ws + off);   off += 256;
  int*   entries = (int*)(ws + off);  off += (size_t)N_EXP * T_TOK * 4;
  float* wlist  = (float*)(ws + off); off += (size_t)N_EXP * T_TOK * 4;
  int*   items  = (int*)(ws + off);   off += 256;

  (void)hipMemsetAsync(d_out, 0, (size_t)out_size * sizeof(float), stream);
  router_kernel<<<dim3(T_TOK), 512, 0, stream>>>(x, gw, logits, tk_idx, tk_w, xb);
  build_lists<<<dim3(N_EXP), 64, 0, stream>>>(tk_idx, tk_w, counts, entries, wlist);
  build_items<<<dim3(1), 64, 0, stream>>>(counts, items);
  moe_gemm1<<<dim3(NITEM * G1_NY), 512, 0, stream>>>(w1, w3, xb, counts, entries, items, hb);
  moe_gemm2<<<dim3(NITEM * G2_NY), 512, 0, stream>>>(w2, hb, counts, entries, wlist, items, out);
}